// Round 19
// baseline (13.717 us; speedup 1.0000x reference)
//
#include <hip/hip_runtime.h>
#include <stdint.h>
#include <math.h>

// ---------------------------------------------------------------------------
// SubsetItems, round 18: bit-exact math (absmax 0.0 r1-r17). TWO dispatches.
// Changes vs r17 (14.31us), last rungs of the chain-split gradient:
//   - k1: noise split across wave pairs — t<128 runs the LONG chain (noise
//     threefry + erfinv + f64 log), 128<=t<256 runs the SHORT chain (mask
//     threefry + flip-max + clip) -> phase wall = max, not sum; combine via
//     LDS; then 4-way split-count sort (r17 scheme, unchanged).
//   - k2: 512 blocks x 256 thr, 4 threads/item (quarter hh searches chunks
//     8hh..8hh+7, ONE 8-wide step-major batch x 8 steps); 8 waves/CU.
// ---------------------------------------------------------------------------

#define NCHUNK 32     // chunks per row
#define CLEN   128    // chunk length

struct TF2 { uint32_t a, b; };

__host__ __device__ inline TF2 threefry2x32(uint32_t k0, uint32_t k1,
                                            uint32_t x0, uint32_t x1) {
  const uint32_t ks2 = k0 ^ k1 ^ 0x1BD11BDAu;
#define TF_ROT(v, d) (uint32_t)(((v) << (d)) | ((v) >> (32 - (d))))
#define TF_RND(r) do { x0 += x1; x1 = TF_ROT(x1, r); x1 ^= x0; } while (0)
  x0 += k0; x1 += k1;
  TF_RND(13); TF_RND(15); TF_RND(26); TF_RND(6);
  x0 += k1; x1 += ks2 + 1u;
  TF_RND(17); TF_RND(29); TF_RND(16); TF_RND(24);
  x0 += ks2; x1 += k0 + 2u;
  TF_RND(13); TF_RND(15); TF_RND(26); TF_RND(6);
  x0 += k0; x1 += k1 + 3u;
  TF_RND(17); TF_RND(29); TF_RND(16); TF_RND(24);
  x0 += k1; x1 += ks2 + 4u;
  TF_RND(13); TF_RND(15); TF_RND(26); TF_RND(6);
  x0 += ks2; x1 += k0 + 5u;
#undef TF_RND
#undef TF_ROT
  return {x0, x1};
}

__host__ __device__ __forceinline__ uint32_t random_bits_at(uint32_t ka, uint32_t kb,
                                                            uint32_t idx) {
  TF2 r = threefry2x32(ka, kb, 0u, idx);
  return r.a ^ r.b;
}

// XLA/CHLO ErfInv f32 (bit-exact, verified r1-r17).
__device__ __forceinline__ float erfinv_f32_xla(float x) {
  float xx = __fmul_rn(x, x);
  float v  = -xx;
  float w;
  if (fabsf(v) < 1e-4f) {
    float t = __fmul_rn(__fadd_rn(__fmul_rn(-0.5f, v), 1.0f), v);
    w = -t;
  } else {
    float t = __fadd_rn(v, 1.0f);
    w = -(float)log((double)t);
  }
  float p;
  if (w < 5.0f) {
    float ww = __fadd_rn(w, -2.5f);
    p = 2.81022636e-08f;
    p = __fadd_rn( 3.43273939e-07f, __fmul_rn(p, ww));
    p = __fadd_rn(-3.5233877e-06f,  __fmul_rn(p, ww));
    p = __fadd_rn(-4.39150654e-06f, __fmul_rn(p, ww));
    p = __fadd_rn( 0.00021858087f,  __fmul_rn(p, ww));
    p = __fadd_rn(-0.00125372503f,  __fmul_rn(p, ww));
    p = __fadd_rn(-0.00417768164f,  __fmul_rn(p, ww));
    p = __fadd_rn( 0.246640727f,    __fmul_rn(p, ww));
    p = __fadd_rn( 1.50140941f,     __fmul_rn(p, ww));
  } else {
    float ww = __fadd_rn(__fsqrt_rn(w), -3.0f);
    p = -0.000200214257f;
    p = __fadd_rn( 0.000100950558f, __fmul_rn(p, ww));
    p = __fadd_rn( 0.00134934322f,  __fmul_rn(p, ww));
    p = __fadd_rn(-0.00367342844f,  __fmul_rn(p, ww));
    p = __fadd_rn( 0.00573950773f,  __fmul_rn(p, ww));
    p = __fadd_rn(-0.0076224613f,   __fmul_rn(p, ww));
    p = __fadd_rn( 0.00943887047f,  __fmul_rn(p, ww));
    p = __fadd_rn( 1.00167406f,     __fmul_rn(p, ww));
    p = __fadd_rn( 2.83297682f,     __fmul_rn(p, ww));
  }
  return __fmul_rn(p, x);
}

// Kernel 1: 256 blocks x 512 threads, one 128-elem chunk per block.
// Phase A (parallel chains): t<128 computes the LONG chain (noise bits ->
// erfinv -> nois); 128<=t<256 computes the SHORT chain (mask bits -> clip x)
// into LDS. Combine: t<128 forms key, writes k64 + jraw.
// Phase B: 4-way split-count sort (quarter h counts 32 compares), scatter.
__global__ __launch_bounds__(512)
void noise_sort_kernel(const float* __restrict__ scores,
                       uint64_t* __restrict__ k64,
                       uint64_t* __restrict__ ksrt,
                       uint32_t k1a, uint32_t k1b, uint32_t k3a, uint32_t k3b,
                       uint32_t rowmask) {
  __shared__ uint64_t jraw[CLEN];
  __shared__ uint64_t jsrt[CLEN];
  __shared__ float    xsh[CLEN];
  __shared__ unsigned short scnt[4][CLEN];
  int t = threadIdx.x;                      // 0..511
  int kk = t & 127, h = t >> 7;             // h = 0..3

  float nois = 0.0f;
  if (t < CLEN) {
    // LONG chain: noise bits -> erfinv -> nois  (element e = blk*128 + t)
    int e = blockIdx.x * CLEN + t;
    uint32_t nbits = random_bits_at(k3a, k3b, (uint32_t)e);
    float f   = __uint_as_float((nbits >> 9) | 0x3f800000u);
    float f01 = __fadd_rn(f, -1.0f);
    const float lo = __uint_as_float(0xBF7FFFFFu);
    float u = __fadd_rn(__fmul_rn(f01, 2.0f), lo);
    u = fmaxf(lo, u);
    float p    = erfinv_f32_xla(u);
    float nrm  = __fmul_rn(__uint_as_float(0x3FB504F3u), p);
    nois = __fmul_rn(nrm, 0.0009765625f);
  } else if (t < 2 * CLEN) {
    // SHORT chain: mask bits -> flip-max -> clip  (element e2 for lane t-128)
    int e2 = blockIdx.x * CLEN + (t - CLEN);
    int b  = e2 >> 12;
    uint32_t mbits = random_bits_at(k1a, k1b, (uint32_t)e2);
    bool mask = ((mbits >> 9) <= 838860u) && ((rowmask >> b) & 1u);
    float s  = scores[e2];
    float sf = scores[32767 - e2];
    float v  = mask ? fmaxf(s, sf) : s;
    xsh[t - CLEN] = fminf(fmaxf(v, -1.0f), 1.0f);
  }
  __syncthreads();

  if (t < CLEN) {
    int e = blockIdx.x * CLEN + t;
    float xnv = __fadd_rn(xsh[t], nois);
    uint32_t ub = __float_as_uint(xnv);
    uint32_t tk = (ub & 0x80000000u) ? ~ub : (ub | 0x80000000u);
    uint64_t key = ((uint64_t)tk << 32) | (uint32_t)(e & 4095);
    k64[e]  = key;
    jraw[t] = key;
  }
  __syncthreads();

  // split count: quarter h compares its key against jraw[h*32 .. h*32+31]
  {
    uint64_t mykey = jraw[kk];
    int r = 0;
    const uint64_t* quart = jraw + h * 32;
#pragma unroll 8
    for (int uu = 0; uu < 32; ++uu) r += (int)(quart[uu] < mykey);
    scnt[h][kk] = (unsigned short)r;
  }
  __syncthreads();

  if (t < CLEN) {
    int r = (int)scnt[0][t] + (int)scnt[1][t] + (int)scnt[2][t] + (int)scnt[3][t];
    jsrt[r] = jraw[t];                      // unique keys -> exact ranks
  }
  __syncthreads();

  if (t < CLEN) ksrt[blockIdx.x * CLEN + t] = jsrt[t];
}

// Kernel 2: 512 blocks x 256 threads (2 blocks/CU, 8 waves/CU). Block
// (row = b>>6, ic = b&63) owns 64 items; 4 threads/item (quarter hh searches
// chunks 8hh..8hh+7, ONE 8-wide step-major batch x 8 steps); LDS combine;
// t<64 scatters idx+weight.
__global__ __launch_bounds__(256)
void rank_out_kernel(const uint64_t* __restrict__ k64,
                     const uint64_t* __restrict__ ksrt,
                     float* __restrict__ out) {
  __shared__ uint64_t ldsrow[4096];         // 32 KB
  __shared__ int prank[4][64];
  int t   = threadIdx.x;                    // 0..255
  int row = blockIdx.x >> 6;
  int ic  = blockIdx.x & 63;

  const ulonglong2* rowp2 = (const ulonglong2*)(ksrt + row * 4096);
#pragma unroll
  for (int q = 0; q < 8; ++q) {
    ulonglong2 v = rowp2[t + q * 256];
    ldsrow[2 * (t + q * 256)]     = v.x;
    ldsrow[2 * (t + q * 256) + 1] = v.y;
  }

  int it = t & 63, hh = t >> 6;             // item slot, chunk-quarter 0..3
  int i  = ic * 64 + it;
  uint64_t ki = k64[row * 4096 + i];        // own (unsorted) key
  __syncthreads();

  const int offs[8] = {63, 31, 15, 7, 3, 1, 0, 0};
  const int incs[8] = {64, 32, 16, 8, 4, 2, 1, 1};

  int pos[8];
#pragma unroll
  for (int m = 0; m < 8; ++m) pos[m] = 0;
  int cbase = hh * 8 * CLEN;
#pragma unroll
  for (int s = 0; s < 8; ++s) {
    uint64_t vv[8];
#pragma unroll
    for (int m = 0; m < 8; ++m) vv[m] = ldsrow[cbase + m * CLEN + pos[m] + offs[s]];
#pragma unroll
    for (int m = 0; m < 8; ++m) pos[m] += (vv[m] < ki) ? incs[s] : 0;
  }
  int r = 0;
#pragma unroll
  for (int m = 0; m < 8; ++m) r += pos[m];
  prank[hh][it] = r;
  __syncthreads();

  if (t < 64) {
    int rank = prank[0][t] + prank[1][t] + prank[2][t] + prank[3][t];
    if (rank >= 2048) {
      int j = rank - 2048;
      int i2 = ic * 64 + t;
      out[row * 2048 + j] = (float)i2;
      out[16384 + row * 2048 + j] = fminf(__fdiv_rn((float)j, 204.8f), 1.0f);
    }
  }
}

extern "C" void kernel_launch(void* const* d_in, const int* in_sizes, int n_in,
                              void* d_out, int out_size, void* d_ws, size_t ws_size,
                              hipStream_t stream) {
  const float* scores = (const float*)d_in[0];
  float* out = (float*)d_out;

  uint64_t* k64  = (uint64_t*)d_ws;                         // 256 KB unsorted
  uint64_t* ksrt = (uint64_t*)d_ws + 32768;                 // 256 KB sorted

  // split(key(42), 3), partitionable layout (verified r1)
  TF2 K1 = threefry2x32(0u, 42u, 0u, 0u);
  TF2 K2 = threefry2x32(0u, 42u, 0u, 1u);
  TF2 K3 = threefry2x32(0u, 42u, 0u, 2u);

  // batch_mask rows on host: uniform(k2,(8,1)) < 0.75
  uint32_t rowmask = 0;
  for (uint32_t b = 0; b < 8; ++b) {
    uint32_t bits = random_bits_at(K2.a, K2.b, b);
    if ((bits >> 9) < 6291456u) rowmask |= (1u << b);
  }

  noise_sort_kernel<<<256, 512, 0, stream>>>(scores, k64, ksrt,
                                             K1.a, K1.b, K3.a, K3.b, rowmask);
  rank_out_kernel<<<512, 256, 0, stream>>>(k64, ksrt, out);
}

// Round 20
// 13.622 us; speedup vs baseline: 1.0070x; 1.0070x over previous
//
#include <hip/hip_runtime.h>
#include <stdint.h>
#include <math.h>

// ---------------------------------------------------------------------------
// SubsetItems, round 19: bit-exact math (absmax 0.0 r1-r18). TWO dispatches.
// Changes vs r18 (13.72us):
//   - k2: 512 blocks x 512 thr, 8 threads/item (eighth hh searches chunks
//     4hh..4hh+3, ONE 4-wide step-major batch x 8 steps); 16 waves/CU.
//   - k1: direct-scatter sorted write (ksrt[blk*128+r] = key; ranks unique)
//     removes the jsrt LDS bounce + one __syncthreads; t<128 keeps its key
//     in a register for the count phase.
// ---------------------------------------------------------------------------

#define NCHUNK 32     // chunks per row
#define CLEN   128    // chunk length

struct TF2 { uint32_t a, b; };

__host__ __device__ inline TF2 threefry2x32(uint32_t k0, uint32_t k1,
                                            uint32_t x0, uint32_t x1) {
  const uint32_t ks2 = k0 ^ k1 ^ 0x1BD11BDAu;
#define TF_ROT(v, d) (uint32_t)(((v) << (d)) | ((v) >> (32 - (d))))
#define TF_RND(r) do { x0 += x1; x1 = TF_ROT(x1, r); x1 ^= x0; } while (0)
  x0 += k0; x1 += k1;
  TF_RND(13); TF_RND(15); TF_RND(26); TF_RND(6);
  x0 += k1; x1 += ks2 + 1u;
  TF_RND(17); TF_RND(29); TF_RND(16); TF_RND(24);
  x0 += ks2; x1 += k0 + 2u;
  TF_RND(13); TF_RND(15); TF_RND(26); TF_RND(6);
  x0 += k0; x1 += k1 + 3u;
  TF_RND(17); TF_RND(29); TF_RND(16); TF_RND(24);
  x0 += k1; x1 += ks2 + 4u;
  TF_RND(13); TF_RND(15); TF_RND(26); TF_RND(6);
  x0 += ks2; x1 += k0 + 5u;
#undef TF_RND
#undef TF_ROT
  return {x0, x1};
}

__host__ __device__ __forceinline__ uint32_t random_bits_at(uint32_t ka, uint32_t kb,
                                                            uint32_t idx) {
  TF2 r = threefry2x32(ka, kb, 0u, idx);
  return r.a ^ r.b;
}

// XLA/CHLO ErfInv f32 (bit-exact, verified r1-r18).
__device__ __forceinline__ float erfinv_f32_xla(float x) {
  float xx = __fmul_rn(x, x);
  float v  = -xx;
  float w;
  if (fabsf(v) < 1e-4f) {
    float t = __fmul_rn(__fadd_rn(__fmul_rn(-0.5f, v), 1.0f), v);
    w = -t;
  } else {
    float t = __fadd_rn(v, 1.0f);
    w = -(float)log((double)t);
  }
  float p;
  if (w < 5.0f) {
    float ww = __fadd_rn(w, -2.5f);
    p = 2.81022636e-08f;
    p = __fadd_rn( 3.43273939e-07f, __fmul_rn(p, ww));
    p = __fadd_rn(-3.5233877e-06f,  __fmul_rn(p, ww));
    p = __fadd_rn(-4.39150654e-06f, __fmul_rn(p, ww));
    p = __fadd_rn( 0.00021858087f,  __fmul_rn(p, ww));
    p = __fadd_rn(-0.00125372503f,  __fmul_rn(p, ww));
    p = __fadd_rn(-0.00417768164f,  __fmul_rn(p, ww));
    p = __fadd_rn( 0.246640727f,    __fmul_rn(p, ww));
    p = __fadd_rn( 1.50140941f,     __fmul_rn(p, ww));
  } else {
    float ww = __fadd_rn(__fsqrt_rn(w), -3.0f);
    p = -0.000200214257f;
    p = __fadd_rn( 0.000100950558f, __fmul_rn(p, ww));
    p = __fadd_rn( 0.00134934322f,  __fmul_rn(p, ww));
    p = __fadd_rn(-0.00367342844f,  __fmul_rn(p, ww));
    p = __fadd_rn( 0.00573950773f,  __fmul_rn(p, ww));
    p = __fadd_rn(-0.0076224613f,   __fmul_rn(p, ww));
    p = __fadd_rn( 0.00943887047f,  __fmul_rn(p, ww));
    p = __fadd_rn( 1.00167406f,     __fmul_rn(p, ww));
    p = __fadd_rn( 2.83297682f,     __fmul_rn(p, ww));
  }
  return __fmul_rn(p, x);
}

// Kernel 1: 256 blocks x 512 threads, one 128-elem chunk per block.
// Phase A: t<128 LONG chain (noise bits -> erfinv), 128<=t<256 SHORT chain
// (mask bits -> clip) into LDS. Combine: t<128 forms key (kept in register),
// writes k64 + jraw. Phase B: 4-way split-count; t<128 direct-scatters the
// sorted key to ksrt[blk*128 + rank] (ranks unique -> exact permutation).
__global__ __launch_bounds__(512)
void noise_sort_kernel(const float* __restrict__ scores,
                       uint64_t* __restrict__ k64,
                       uint64_t* __restrict__ ksrt,
                       uint32_t k1a, uint32_t k1b, uint32_t k3a, uint32_t k3b,
                       uint32_t rowmask) {
  __shared__ uint64_t jraw[CLEN];
  __shared__ float    xsh[CLEN];
  __shared__ unsigned short scnt[4][CLEN];
  int t = threadIdx.x;                      // 0..511
  int kk = t & 127, h = t >> 7;             // h = 0..3

  float nois = 0.0f;
  if (t < CLEN) {
    // LONG chain: noise bits -> erfinv -> nois  (element e = blk*128 + t)
    int e = blockIdx.x * CLEN + t;
    uint32_t nbits = random_bits_at(k3a, k3b, (uint32_t)e);
    float f   = __uint_as_float((nbits >> 9) | 0x3f800000u);
    float f01 = __fadd_rn(f, -1.0f);
    const float lo = __uint_as_float(0xBF7FFFFFu);
    float u = __fadd_rn(__fmul_rn(f01, 2.0f), lo);
    u = fmaxf(lo, u);
    float p    = erfinv_f32_xla(u);
    float nrm  = __fmul_rn(__uint_as_float(0x3FB504F3u), p);
    nois = __fmul_rn(nrm, 0.0009765625f);
  } else if (t < 2 * CLEN) {
    // SHORT chain: mask bits -> flip-max -> clip  (element e2 for lane t-128)
    int e2 = blockIdx.x * CLEN + (t - CLEN);
    int b  = e2 >> 12;
    uint32_t mbits = random_bits_at(k1a, k1b, (uint32_t)e2);
    bool mask = ((mbits >> 9) <= 838860u) && ((rowmask >> b) & 1u);
    float s  = scores[e2];
    float sf = scores[32767 - e2];
    float v  = mask ? fmaxf(s, sf) : s;
    xsh[t - CLEN] = fminf(fmaxf(v, -1.0f), 1.0f);
  }
  __syncthreads();

  uint64_t keyreg = 0;
  if (t < CLEN) {
    int e = blockIdx.x * CLEN + t;
    float xnv = __fadd_rn(xsh[t], nois);
    uint32_t ub = __float_as_uint(xnv);
    uint32_t tk = (ub & 0x80000000u) ? ~ub : (ub | 0x80000000u);
    keyreg = ((uint64_t)tk << 32) | (uint32_t)(e & 4095);
    k64[e]  = keyreg;
    jraw[t] = keyreg;
  }
  __syncthreads();

  // split count: quarter h compares its key against jraw[h*32 .. h*32+31]
  {
    uint64_t mykey = (t < CLEN) ? keyreg : jraw[kk];
    int r = 0;
    const uint64_t* quart = jraw + h * 32;
#pragma unroll 8
    for (int uu = 0; uu < 32; ++uu) r += (int)(quart[uu] < mykey);
    scnt[h][kk] = (unsigned short)r;
  }
  __syncthreads();

  if (t < CLEN) {
    int r = (int)scnt[0][t] + (int)scnt[1][t] + (int)scnt[2][t] + (int)scnt[3][t];
    ksrt[blockIdx.x * CLEN + r] = keyreg;   // ranks unique -> exact scatter
  }
}

// Kernel 2: 512 blocks x 512 threads (2 blocks/CU, 16 waves/CU). Block
// (row = b>>6, ic = b&63) owns 64 items; 8 threads/item (eighth hh searches
// chunks 4hh..4hh+3, ONE 4-wide step-major batch x 8 steps); LDS combine;
// t<64 scatters idx+weight.
__global__ __launch_bounds__(512)
void rank_out_kernel(const uint64_t* __restrict__ k64,
                     const uint64_t* __restrict__ ksrt,
                     float* __restrict__ out) {
  __shared__ uint64_t ldsrow[4096];         // 32 KB
  __shared__ int prank[8][64];
  int t   = threadIdx.x;                    // 0..511
  int row = blockIdx.x >> 6;
  int ic  = blockIdx.x & 63;

  const ulonglong2* rowp2 = (const ulonglong2*)(ksrt + row * 4096);
#pragma unroll
  for (int q = 0; q < 4; ++q) {
    ulonglong2 v = rowp2[t + q * 512];
    ldsrow[2 * (t + q * 512)]     = v.x;
    ldsrow[2 * (t + q * 512) + 1] = v.y;
  }

  int it = t & 63, hh = t >> 6;             // item slot, chunk-eighth 0..7
  int i  = ic * 64 + it;
  uint64_t ki = k64[row * 4096 + i];        // own (unsorted) key
  __syncthreads();

  const int offs[8] = {63, 31, 15, 7, 3, 1, 0, 0};
  const int incs[8] = {64, 32, 16, 8, 4, 2, 1, 1};

  int pos[4];
#pragma unroll
  for (int m = 0; m < 4; ++m) pos[m] = 0;
  int cbase = hh * 4 * CLEN;
#pragma unroll
  for (int s = 0; s < 8; ++s) {
    uint64_t vv[4];
#pragma unroll
    for (int m = 0; m < 4; ++m) vv[m] = ldsrow[cbase + m * CLEN + pos[m] + offs[s]];
#pragma unroll
    for (int m = 0; m < 4; ++m) pos[m] += (vv[m] < ki) ? incs[s] : 0;
  }
  int r = pos[0] + pos[1] + pos[2] + pos[3];
  prank[hh][it] = r;
  __syncthreads();

  if (t < 64) {
    int rank = prank[0][t] + prank[1][t] + prank[2][t] + prank[3][t]
             + prank[4][t] + prank[5][t] + prank[6][t] + prank[7][t];
    if (rank >= 2048) {
      int j = rank - 2048;
      int i2 = ic * 64 + t;
      out[row * 2048 + j] = (float)i2;
      out[16384 + row * 2048 + j] = fminf(__fdiv_rn((float)j, 204.8f), 1.0f);
    }
  }
}

extern "C" void kernel_launch(void* const* d_in, const int* in_sizes, int n_in,
                              void* d_out, int out_size, void* d_ws, size_t ws_size,
                              hipStream_t stream) {
  const float* scores = (const float*)d_in[0];
  float* out = (float*)d_out;

  uint64_t* k64  = (uint64_t*)d_ws;                         // 256 KB unsorted
  uint64_t* ksrt = (uint64_t*)d_ws + 32768;                 // 256 KB sorted

  // split(key(42), 3), partitionable layout (verified r1)
  TF2 K1 = threefry2x32(0u, 42u, 0u, 0u);
  TF2 K2 = threefry2x32(0u, 42u, 0u, 1u);
  TF2 K3 = threefry2x32(0u, 42u, 0u, 2u);

  // batch_mask rows on host: uniform(k2,(8,1)) < 0.75
  uint32_t rowmask = 0;
  for (uint32_t b = 0; b < 8; ++b) {
    uint32_t bits = random_bits_at(K2.a, K2.b, b);
    if ((bits >> 9) < 6291456u) rowmask |= (1u << b);
  }

  noise_sort_kernel<<<256, 512, 0, stream>>>(scores, k64, ksrt,
                                             K1.a, K1.b, K3.a, K3.b, rowmask);
  rank_out_kernel<<<512, 512, 0, stream>>>(k64, ksrt, out);
}